// Round 5
// baseline (102.878 us; speedup 1.0000x reference)
//
#include <hip/hip_runtime.h>
#include <hip/hip_bf16.h>
#include <stdint.h>

#define M_DIM 8192
#define N_DIM 2048
#define K_DIM 2048

typedef __attribute__((ext_vector_type(8))) short bf16x8;
typedef __attribute__((ext_vector_type(8))) short short8;
typedef __attribute__((ext_vector_type(4))) float f32x4;
typedef __attribute__((ext_vector_type(16))) float f32x16;

static __device__ __forceinline__ unsigned short f2bf(float f) {
  union { float f; unsigned u; } a; a.f = f;
  unsigned u = a.u;
  u += 0x7FFFu + ((u >> 16) & 1u);   // round-to-nearest-even
  return (unsigned short)(u >> 16);
}

static __device__ __forceinline__ void async16(void* lds, const void* g) {
  __builtin_amdgcn_global_load_lds(
      (const __attribute__((address_space(1))) unsigned int*)g,
      (__attribute__((address_space(3))) unsigned int*)lds, 16, 0, 0);
}

#define BAR()                                \
  do {                                       \
    asm volatile("" ::: "memory");           \
    __builtin_amdgcn_s_barrier();            \
    asm volatile("" ::: "memory");           \
  } while (0)
#define VMCNT(n) asm volatile("s_waitcnt vmcnt(" #n ")" ::: "memory")

// ---- kernel 1: convert + transpose W [K][N] -> Wt [N][K] bf16; fused
// W[:,0] extraction (bx==0 blocks see n0==0 and emit wcol from the tile) ----
__global__ __launch_bounds__(256) void k_transW(const float* __restrict__ W,
                                                unsigned short* __restrict__ Wt,
                                                float* __restrict__ wcol) {
  __shared__ float tile[64][65];
  const int bx = blockIdx.x & 31;
  const int by = blockIdx.x >> 5;
  const int n0 = bx * 64, k0 = by * 64;
  const int t = threadIdx.x;
  #pragma unroll
  for (int i = 0; i < 16; ++i) {
    int lin = i * 256 + t;
    int r = lin >> 6, c = lin & 63;
    float v = W[(size_t)(k0 + r) * N_DIM + n0 + c];
    tile[r][c] = v;
    if (bx == 0 && c == 0) wcol[k0 + r] = v;
  }
  __syncthreads();
  #pragma unroll
  for (int i = 0; i < 16; ++i) {
    int lin = i * 256 + t;
    int r = lin >> 6, c = lin & 63;
    Wt[(size_t)(n0 + r) * K_DIM + k0 + c] = f2bf(tile[c][r]);
  }
}

// ---- kernel 2: X fp32->bf16 + fused fp64 row-dot with W[:,0] -> adj ----
__global__ __launch_bounds__(256) void k_convX(const float* __restrict__ X,
    const float* __restrict__ wcol, const float* __restrict__ b,
    unsigned short* __restrict__ Xb, float* __restrict__ adj) {
  const int m = blockIdx.x;
  const int t = threadIdx.x;
  const float4* xr = (const float4*)(X + (size_t)m * K_DIM);
  const float4* wc = (const float4*)wcol;
  float4 x0 = xr[2 * t], x1 = xr[2 * t + 1];
  float4 w0 = wc[2 * t], w1 = wc[2 * t + 1];
  short8 o;
  o[0] = (short)f2bf(x0.x); o[1] = (short)f2bf(x0.y);
  o[2] = (short)f2bf(x0.z); o[3] = (short)f2bf(x0.w);
  o[4] = (short)f2bf(x1.x); o[5] = (short)f2bf(x1.y);
  o[6] = (short)f2bf(x1.z); o[7] = (short)f2bf(x1.w);
  *(short8*)(Xb + (size_t)m * K_DIM + t * 8) = o;
  double s = (double)x0.x * w0.x + (double)x0.y * w0.y +
             (double)x0.z * w0.z + (double)x0.w * w0.w +
             (double)x1.x * w1.x + (double)x1.y * w1.y +
             (double)x1.z * w1.z + (double)x1.w * w1.w;
  #pragma unroll
  for (int off = 32; off > 0; off >>= 1) s += __shfl_down(s, off, 64);
  __shared__ double red[4];
  if ((t & 63) == 0) red[t >> 6] = s;
  __syncthreads();
  if (t == 0) {
    double tot = red[0] + red[1] + red[2] + red[3] + (double)b[0];
    adj[m] = (tot > 0.5) ? 1.0f : -1.0f;
  }
}

// ---- kernel 3: 256x256 4-phase/K-tile MFMA GEMM, 32x32x16 shape ----
// Sync skeleton (barriers/stages/vmcnt) IDENTICAL to round 4 (verified
// race-free). Only read offsets, MFMA shape, and epilogue changed.
// Per-wave output 128x64 = 4 m-blocks(32) x 2 n-blocks(32); acc[4][2] f32x16.
// A-frag (32x32x16): row=l&31, k=(l>>5)*8; C/D: col=l&31,
// row=(reg&3)+8*(reg>>2)+4*(l>>5).
__device__ __forceinline__ void stage_unit(char* ldsc,
    const unsigned short* __restrict__ src, int row0, int kt,
    int isB, int sel, int wid, int l) {
  char* base = ldsc + (size_t)(kt & 1) * 65536 + (size_t)isB * 32768;
  #pragma unroll
  for (int j = 0; j < 2; ++j) {
    int s = wid * 2 + j;               // [0,16) subtile slots of this unit
    int sub_c = s & 1;
    int idx = s >> 1;                  // [0,8)
    int sub_r = isB ? ((idx & 1) + (idx >> 1) * 4 + sel * 2)
                    : ((idx & 3) + ((idx & 4) ? 8 : 0) + sel * 4);
    int grow = row0 + sub_r * 16 + (l >> 2);
    int gcol = kt * 64 + sub_c * 32 + (((l & 3) * 8) ^ ((l & 32) >> 1));
    async16(base + (size_t)(sub_r * 2 + sub_c) * 1024,
            src + (size_t)grow * K_DIM + gcol);
  }
}

__global__ __launch_bounds__(512, 1) void k_gemm8(
    const unsigned short* __restrict__ A,   // Xb [M][K] bf16
    const unsigned short* __restrict__ B,   // Wt [N][K] bf16
    const float* __restrict__ bias,
    const float* __restrict__ adj,
    float* __restrict__ out) {
  __shared__ unsigned short lds[2 * 2 * 256 * 64];   // 128 KB
  char* ldsc = (char*)lds;

  const int t = threadIdx.x;
  const int wid = t >> 6, l = t & 63;
  const int wm = wid >> 2, wn = wid & 3;

  // XCD-bijective swizzle (nwg = 256, 256 % 8 == 0)
  const int bid = blockIdx.x;
  const int swz = (bid & 7) * 32 + (bid >> 3);
  const int bm = swz >> 3, bn = swz & 7;
  const int m0 = bm * 256, n0 = bn * 256;

  // per-lane LDS read components (32x32x16 fragment addressing)
  const int lane_sub = ((l & 31) >> 4) * 2048;   // upper/lower 16-row subtile
  const int lane_row = (l & 15) * 64;
  const int lane_kc  = (l >> 5) * 16;            // k-chunk byte offset
  const int lane_swz = (l & 8) << 2;             // write-side XOR (rows 8-15)

  f32x16 acc[4][2] = {};

#define STG(isB, sel, kt) \
  stage_unit(ldsc, (isB) ? B : A, (isB) ? n0 : m0, kt, isB, sel, wid, l)

#define RD_A(MH)                                                            \
  _Pragma("unroll") for (int mb2 = 0; mb2 < 2; ++mb2) {                     \
    const char* abase = ab + ((size_t)(wm * 8 + ((MH) * 2 + mb2) * 2)) *    \
                                 2048 + lane_sub + lane_row;                \
    _Pragma("unroll") for (int ks = 0; ks < 4; ++ks)                        \
      af[mb2][ks] = *(const bf16x8*)(abase + (ks >> 1) * 1024 +             \
                        ((((ks & 1) * 32) + lane_kc) ^ lane_swz));          \
  }

#define RD_B(DST, NH)                                                       \
  {                                                                         \
    const char* bbase = bb + ((size_t)(wn * 4 + (NH) * 2)) * 2048 +         \
                        lane_sub + lane_row;                                \
    _Pragma("unroll") for (int ks = 0; ks < 4; ++ks)                        \
      DST[ks] = *(const bf16x8*)(bbase + (ks >> 1) * 1024 +                 \
                    ((((ks & 1) * 32) + lane_kc) ^ lane_swz));              \
  }

#define PHASE(BUF, MH, NH, READ_STMT, STAGE_STMT, WAIT_STMT)                \
  {                                                                         \
    const char* ab = ldsc + (size_t)(BUF) * 65536;                          \
    const char* bb = ab + 32768;                                            \
    (void)ab; (void)bb;                                                     \
    READ_STMT;                                                              \
    STAGE_STMT;                                                             \
    BAR();                                                                  \
    __builtin_amdgcn_s_setprio(1);                                          \
    _Pragma("unroll") for (int ks = 0; ks < 4; ++ks)                        \
      _Pragma("unroll") for (int mb2 = 0; mb2 < 2; ++mb2) {                 \
        acc[(MH) * 2 + mb2][NH] = __builtin_amdgcn_mfma_f32_32x32x16_bf16(  \
            af[mb2][ks], ((NH) ? bv1 : bv0)[ks], acc[(MH) * 2 + mb2][NH],   \
            0, 0, 0);                                                       \
      }                                                                     \
    __builtin_amdgcn_s_setprio(0);                                          \
    WAIT_STMT;                                                              \
    BAR();                                                                  \
  }

  // ---- prologue: stage tile 0 (A0,B0,B1,A1), retire all but A1(0) ----
  STG(0, 0, 0); STG(1, 0, 0); STG(1, 1, 0); STG(0, 1, 0);
  VMCNT(2);
  BAR();

  // ---- main loop: blocks j = 0..30, staging tile j+1 ----
  for (int j = 0; j < 31; ++j) {
    const int buf = j & 1;
    const int nt = j + 1;
    bf16x8 af[2][4], bv0[4], bv1[4];
    PHASE(buf, 0, 0, RD_A(0); RD_B(bv0, 0); RD_B(bv1, 1),
          STG(0, 0, nt), );                          // P1: stage A0(j+1)
    PHASE(buf, 0, 1, , STG(1, 0, nt), VMCNT(4));     // P2: B0(j+1); retire A1(j)
    PHASE(buf, 1, 0, RD_A(1), STG(1, 1, nt), );      // P3: stage B1(j+1)
    PHASE(buf, 1, 1, , STG(0, 1, nt), VMCNT(2));     // P4: A1(j+1); retire rest
  }
  // ---- peeled last block: tile 31 in buf1, drain ----
  {
    bf16x8 af[2][4], bv0[4], bv1[4];
    PHASE(1, 0, 0, RD_A(0); RD_B(bv0, 0); RD_B(bv1, 1), , );
    PHASE(1, 0, 1, , , VMCNT(0));                    // retire A1(31)
    PHASE(1, 1, 0, RD_A(1), , );
    PHASE(1, 1, 1, , , );
  }

#undef PHASE
#undef RD_A
#undef RD_B
#undef STG

  // ---- epilogue: bias + per-row +/-1 (32x32 C/D layout) ----
  #pragma unroll
  for (int mb = 0; mb < 4; ++mb) {
    #pragma unroll
    for (int nb = 0; nb < 2; ++nb) {
      const int col = n0 + wn * 64 + nb * 32 + (l & 31);
      const float bvs = bias[col];
      #pragma unroll
      for (int rg = 0; rg < 4; ++rg) {
        const int rowb = m0 + wm * 128 + mb * 32 + rg * 8 + 4 * (l >> 5);
        const float4 adjv = *(const float4*)&adj[rowb];
        #pragma unroll
        for (int rr = 0; rr < 4; ++rr)
          out[(size_t)(rowb + rr) * N_DIM + col] =
              acc[mb][nb][rg * 4 + rr] + bvs + adjv[rr];
      }
    }
  }
}

// ---- fallback path (ws too small): fp32 LDS-tiled GEMM + row adjust ----
__global__ __launch_bounds__(256) void k_gemm_f32(const float* __restrict__ X,
    const float* __restrict__ W, const float* __restrict__ b,
    float* __restrict__ out) {
  __shared__ float As[16][16];
  __shared__ float Bs[16][17];
  const int bn = blockIdx.x & 127, bm = blockIdx.x >> 7;
  const int tx = threadIdx.x & 15, ty = threadIdx.x >> 4;
  const int row = bm * 16 + ty, col = bn * 16 + tx;
  float acc = 0.f;
  for (int k0 = 0; k0 < K_DIM; k0 += 16) {
    As[ty][tx] = X[(size_t)row * K_DIM + k0 + tx];
    Bs[ty][tx] = W[(size_t)(k0 + ty) * N_DIM + col];
    __syncthreads();
    #pragma unroll
    for (int kk = 0; kk < 16; ++kk) acc += As[ty][kk] * Bs[kk][tx];
    __syncthreads();
  }
  out[(size_t)row * N_DIM + col] = acc + b[col];
}

__global__ __launch_bounds__(256) void k_rowadj(float* __restrict__ out) {
  const int m = blockIdx.x;
  const float c0 = out[(size_t)m * N_DIM];
  __syncthreads();
  const float a = (c0 > 0.5f) ? 1.0f : -1.0f;
  for (int n = threadIdx.x; n < N_DIM; n += 256)
    out[(size_t)m * N_DIM + n] += a;
}

extern "C" void kernel_launch(void* const* d_in, const int* in_sizes, int n_in,
                              void* d_out, int out_size, void* d_ws, size_t ws_size,
                              hipStream_t stream) {
  const float* X = (const float*)d_in[0];
  const float* W = (const float*)d_in[1];
  const float* b = (const float*)d_in[2];
  float* out = (float*)d_out;

  const size_t XB_OFF   = 0;
  const size_t WT_OFF   = (size_t)M_DIM * K_DIM * 2;        // 32 MB
  const size_t ADJ_OFF  = WT_OFF + (size_t)N_DIM * K_DIM * 2;
  const size_t WCOL_OFF = ADJ_OFF + (size_t)M_DIM * 4;
  const size_t NEED     = WCOL_OFF + (size_t)K_DIM * 4;     // ~40 MB

  if (ws_size >= NEED) {
    unsigned short* Xb  = (unsigned short*)((char*)d_ws + XB_OFF);
    unsigned short* Wt  = (unsigned short*)((char*)d_ws + WT_OFF);
    float* adj  = (float*)((char*)d_ws + ADJ_OFF);
    float* wcol = (float*)((char*)d_ws + WCOL_OFF);
    k_transW<<<dim3(1024), dim3(256), 0, stream>>>(W, Wt, wcol);
    k_convX<<<dim3(M_DIM), dim3(256), 0, stream>>>(X, wcol, b, Xb, adj);
    k_gemm8<<<dim3((M_DIM / 256) * (N_DIM / 256)), dim3(512), 0, stream>>>(
        Xb, Wt, b, adj, out);
  } else {
    k_gemm_f32<<<dim3((M_DIM / 16) * (N_DIM / 16)), dim3(256), 0, stream>>>(
        X, W, b, out);
    k_rowadj<<<dim3(M_DIM), dim3(256), 0, stream>>>(out);
  }
}

// Round 6
// 102.594 us; speedup vs baseline: 1.0028x; 1.0028x over previous
//
#include <hip/hip_runtime.h>
#include <hip/hip_bf16.h>
#include <stdint.h>

#define M_DIM 8192
#define N_DIM 2048
#define K_DIM 2048

typedef __attribute__((ext_vector_type(8))) short bf16x8;
typedef __attribute__((ext_vector_type(8))) short short8;
typedef __attribute__((ext_vector_type(4))) float f32x4;
typedef __attribute__((ext_vector_type(16))) float f32x16;

static __device__ __forceinline__ unsigned short f2bf(float f) {
  union { float f; unsigned u; } a; a.f = f;
  unsigned u = a.u;
  u += 0x7FFFu + ((u >> 16) & 1u);   // round-to-nearest-even
  return (unsigned short)(u >> 16);
}

static __device__ __forceinline__ void async16(void* lds, const void* g) {
  __builtin_amdgcn_global_load_lds(
      (const __attribute__((address_space(1))) unsigned int*)g,
      (__attribute__((address_space(3))) unsigned int*)lds, 16, 0, 0);
}

#define BAR()                                \
  do {                                       \
    asm volatile("" ::: "memory");           \
    __builtin_amdgcn_s_barrier();            \
    asm volatile("" ::: "memory");           \
  } while (0)
#define VMCNT(n) asm volatile("s_waitcnt vmcnt(" #n ")" ::: "memory")

// ---- kernel 1: convert + transpose W [K][N] -> Wt [N][K] bf16; fused
// W[:,0] extraction ----
__global__ __launch_bounds__(256) void k_transW(const float* __restrict__ W,
                                                unsigned short* __restrict__ Wt,
                                                float* __restrict__ wcol) {
  __shared__ float tile[64][65];
  const int bx = blockIdx.x & 31;
  const int by = blockIdx.x >> 5;
  const int n0 = bx * 64, k0 = by * 64;
  const int t = threadIdx.x;
  #pragma unroll
  for (int i = 0; i < 16; ++i) {
    int lin = i * 256 + t;
    int r = lin >> 6, c = lin & 63;
    float v = W[(size_t)(k0 + r) * N_DIM + n0 + c];
    tile[r][c] = v;
    if (bx == 0 && c == 0) wcol[k0 + r] = v;
  }
  __syncthreads();
  #pragma unroll
  for (int i = 0; i < 16; ++i) {
    int lin = i * 256 + t;
    int r = lin >> 6, c = lin & 63;
    Wt[(size_t)(n0 + r) * K_DIM + k0 + c] = f2bf(tile[c][r]);
  }
}

// ---- kernel 2: X fp32->bf16 + fused fp64 row-dot with W[:,0] -> adj ----
__global__ __launch_bounds__(256) void k_convX(const float* __restrict__ X,
    const float* __restrict__ wcol, const float* __restrict__ b,
    unsigned short* __restrict__ Xb, float* __restrict__ adj) {
  const int m = blockIdx.x;
  const int t = threadIdx.x;
  const float4* xr = (const float4*)(X + (size_t)m * K_DIM);
  const float4* wc = (const float4*)wcol;
  float4 x0 = xr[2 * t], x1 = xr[2 * t + 1];
  float4 w0 = wc[2 * t], w1 = wc[2 * t + 1];
  short8 o;
  o[0] = (short)f2bf(x0.x); o[1] = (short)f2bf(x0.y);
  o[2] = (short)f2bf(x0.z); o[3] = (short)f2bf(x0.w);
  o[4] = (short)f2bf(x1.x); o[5] = (short)f2bf(x1.y);
  o[6] = (short)f2bf(x1.z); o[7] = (short)f2bf(x1.w);
  *(short8*)(Xb + (size_t)m * K_DIM + t * 8) = o;
  double s = (double)x0.x * w0.x + (double)x0.y * w0.y +
             (double)x0.z * w0.z + (double)x0.w * w0.w +
             (double)x1.x * w1.x + (double)x1.y * w1.y +
             (double)x1.z * w1.z + (double)x1.w * w1.w;
  #pragma unroll
  for (int off = 32; off > 0; off >>= 1) s += __shfl_down(s, off, 64);
  __shared__ double red[4];
  if ((t & 63) == 0) red[t >> 6] = s;
  __syncthreads();
  if (t == 0) {
    double tot = red[0] + red[1] + red[2] + red[3] + (double)b[0];
    adj[m] = (tot > 0.5) ? 1.0f : -1.0f;
  }
}

// ---- kernel 3: 256x256 4-phase/K-tile MFMA GEMM, 32x32x16 shape,
// 32-row x 16-k subtiles (1024B) ----
// Subtile grid per operand: 8 sr x 4 sc; base = (sr*4+sc)*1024.
// Lane fragment (row=l&31, khalf=l>>5) = byte (l&31)*32+(l>>5)*16 of ONE
// subtile -> every wave b128 read completely covers one contiguous 1024B
// region (round-4-proven conflict-free property). No swizzle needed.
// Stage: lane l16 writes byte l16*16 (HW-linear) <- global row sr*32+(l16>>1),
// k sc*16+(l16&1)*8. Sync skeleton (stage order A0,B0,B1,A1; vmcnt(4)@P2,
// vmcnt(2)@P4) byte-identical to rounds 3-5 (HW-validated race-free).
// Units: A0: sr{0,1,4,5} (read P1/P2), A1: sr{2,3,6,7} (read P3/P4),
//        B0: even sr (NH0), B1: odd sr (NH1).
__device__ __forceinline__ void stage_unit(char* ldsc,
    const unsigned short* __restrict__ src, int row0, int kt,
    int isB, int sel, int wid, int l) {
  char* base = ldsc + (size_t)(kt & 1) * 65536 + (size_t)isB * 32768;
  #pragma unroll
  for (int j = 0; j < 2; ++j) {
    int idx = wid * 2 + j;             // [0,16) subtile slots of this unit
    int q = idx >> 2, sc = idx & 3;
    int sr = isB ? (q * 2 + sel) : ((q & 1) + sel * 2 + (q >> 1) * 4);
    int grow = row0 + sr * 32 + (l >> 1);
    int gcol = kt * 64 + sc * 16 + (l & 1) * 8;
    async16(base + (size_t)(sr * 4 + sc) * 1024,
            src + (size_t)grow * K_DIM + gcol);
  }
}

__global__ __launch_bounds__(512, 1) void k_gemm8(
    const unsigned short* __restrict__ A,   // Xb [M][K] bf16
    const unsigned short* __restrict__ B,   // Wt [N][K] bf16
    const float* __restrict__ bias,
    const float* __restrict__ adj,
    float* __restrict__ out) {
  __shared__ unsigned short lds[2 * 2 * 256 * 64];   // 128 KB
  char* ldsc = (char*)lds;

  const int t = threadIdx.x;
  const int wid = t >> 6, l = t & 63;
  const int wm = wid >> 2, wn = wid & 3;

  // XCD-bijective swizzle (nwg = 256, 256 % 8 == 0)
  const int bid = blockIdx.x;
  const int swz = (bid & 7) * 32 + (bid >> 3);
  const int bm = swz >> 3, bn = swz & 7;
  const int m0 = bm * 256, n0 = bn * 256;

  const int lane_off = (l & 31) * 32 + (l >> 5) * 16;

  f32x16 acc[4][2] = {};

#define STG(isB, sel, kt) \
  stage_unit(ldsc, (isB) ? B : A, (isB) ? n0 : m0, kt, isB, sel, wid, l)

#define RD_A(MH)                                                            \
  _Pragma("unroll") for (int mb2 = 0; mb2 < 2; ++mb2) {                     \
    const char* abase = ab +                                                \
        (size_t)((wm * 4 + (MH) * 2 + mb2) * 4) * 1024 + lane_off;          \
    _Pragma("unroll") for (int ks = 0; ks < 4; ++ks)                        \
      af[mb2][ks] = *(const bf16x8*)(abase + ks * 1024);                    \
  }

#define RD_B(DST, NH)                                                       \
  {                                                                         \
    const char* bbase = bb +                                                \
        (size_t)((wn * 2 + (NH)) * 4) * 1024 + lane_off;                    \
    _Pragma("unroll") for (int ks = 0; ks < 4; ++ks)                        \
      DST[ks] = *(const bf16x8*)(bbase + ks * 1024);                        \
  }

#define PHASE(BUF, MH, NH, READ_STMT, STAGE_STMT, WAIT_STMT)                \
  {                                                                         \
    const char* ab = ldsc + (size_t)(BUF) * 65536;                          \
    const char* bb = ab + 32768;                                            \
    (void)ab; (void)bb;                                                     \
    READ_STMT;                                                              \
    STAGE_STMT;                                                             \
    BAR();                                                                  \
    __builtin_amdgcn_s_setprio(1);                                          \
    _Pragma("unroll") for (int ks = 0; ks < 4; ++ks)                        \
      _Pragma("unroll") for (int mb2 = 0; mb2 < 2; ++mb2) {                 \
        acc[(MH) * 2 + mb2][NH] = __builtin_amdgcn_mfma_f32_32x32x16_bf16(  \
            af[mb2][ks], ((NH) ? bv1 : bv0)[ks], acc[(MH) * 2 + mb2][NH],   \
            0, 0, 0);                                                       \
      }                                                                     \
    __builtin_amdgcn_s_setprio(0);                                          \
    WAIT_STMT;                                                              \
    BAR();                                                                  \
  }

  // ---- prologue: stage tile 0 (A0,B0,B1,A1), retire all but A1(0) ----
  STG(0, 0, 0); STG(1, 0, 0); STG(1, 1, 0); STG(0, 1, 0);
  VMCNT(2);
  BAR();

  // ---- main loop: blocks j = 0..30, staging tile j+1 ----
  for (int j = 0; j < 31; ++j) {
    const int buf = j & 1;
    const int nt = j + 1;
    bf16x8 af[2][4], bv0[4], bv1[4];
    PHASE(buf, 0, 0, RD_A(0); RD_B(bv0, 0); RD_B(bv1, 1),
          STG(0, 0, nt), );                          // P1: stage A0(j+1)
    PHASE(buf, 0, 1, , STG(1, 0, nt), VMCNT(4));     // P2: B0(j+1); retire A1(j)
    PHASE(buf, 1, 0, RD_A(1), STG(1, 1, nt), );      // P3: stage B1(j+1)
    PHASE(buf, 1, 1, , STG(0, 1, nt), VMCNT(2));     // P4: A1(j+1); retire rest
  }
  // ---- peeled last block: tile 31 in buf1, drain ----
  {
    bf16x8 af[2][4], bv0[4], bv1[4];
    PHASE(1, 0, 0, RD_A(0); RD_B(bv0, 0); RD_B(bv1, 1), , );
    PHASE(1, 0, 1, , , VMCNT(0));                    // retire A1(31)
    PHASE(1, 1, 0, RD_A(1), , );
    PHASE(1, 1, 1, , , );
  }

#undef PHASE
#undef RD_A
#undef RD_B
#undef STG

  // ---- epilogue: bias + per-row +/-1 (32x32 C/D layout, round-5 validated) ----
  #pragma unroll
  for (int mb = 0; mb < 4; ++mb) {
    #pragma unroll
    for (int nb = 0; nb < 2; ++nb) {
      const int col = n0 + wn * 64 + nb * 32 + (l & 31);
      const float bvs = bias[col];
      #pragma unroll
      for (int rg = 0; rg < 4; ++rg) {
        const int rowb = m0 + wm * 128 + mb * 32 + rg * 8 + 4 * (l >> 5);
        const float4 adjv = *(const float4*)&adj[rowb];
        #pragma unroll
        for (int rr = 0; rr < 4; ++rr)
          out[(size_t)(rowb + rr) * N_DIM + col] =
              acc[mb][nb][rg * 4 + rr] + bvs + adjv[rr];
      }
    }
  }
}

// ---- fallback path (ws too small): fp32 LDS-tiled GEMM + row adjust ----
__global__ __launch_bounds__(256) void k_gemm_f32(const float* __restrict__ X,
    const float* __restrict__ W, const float* __restrict__ b,
    float* __restrict__ out) {
  __shared__ float As[16][16];
  __shared__ float Bs[16][17];
  const int bn = blockIdx.x & 127, bm = blockIdx.x >> 7;
  const int tx = threadIdx.x & 15, ty = threadIdx.x >> 4;
  const int row = bm * 16 + ty, col = bn * 16 + tx;
  float acc = 0.f;
  for (int k0 = 0; k0 < K_DIM; k0 += 16) {
    As[ty][tx] = X[(size_t)row * K_DIM + k0 + tx];
    Bs[ty][tx] = W[(size_t)(k0 + ty) * N_DIM + col];
    __syncthreads();
    #pragma unroll
    for (int kk = 0; kk < 16; ++kk) acc += As[ty][kk] * Bs[kk][tx];
    __syncthreads();
  }
  out[(size_t)row * N_DIM + col] = acc + b[col];
}

__global__ __launch_bounds__(256) void k_rowadj(float* __restrict__ out) {
  const int m = blockIdx.x;
  const float c0 = out[(size_t)m * N_DIM];
  __syncthreads();
  const float a = (c0 > 0.5f) ? 1.0f : -1.0f;
  for (int n = threadIdx.x; n < N_DIM; n += 256)
    out[(size_t)m * N_DIM + n] += a;
}

extern "C" void kernel_launch(void* const* d_in, const int* in_sizes, int n_in,
                              void* d_out, int out_size, void* d_ws, size_t ws_size,
                              hipStream_t stream) {
  const float* X = (const float*)d_in[0];
  const float* W = (const float*)d_in[1];
  const float* b = (const float*)d_in[2];
  float* out = (float*)d_out;

  const size_t XB_OFF   = 0;
  const size_t WT_OFF   = (size_t)M_DIM * K_DIM * 2;        // 32 MB
  const size_t ADJ_OFF  = WT_OFF + (size_t)N_DIM * K_DIM * 2;
  const size_t WCOL_OFF = ADJ_OFF + (size_t)M_DIM * 4;
  const size_t NEED     = WCOL_OFF + (size_t)K_DIM * 4;     // ~40 MB

  if (ws_size >= NEED) {
    unsigned short* Xb  = (unsigned short*)((char*)d_ws + XB_OFF);
    unsigned short* Wt  = (unsigned short*)((char*)d_ws + WT_OFF);
    float* adj  = (float*)((char*)d_ws + ADJ_OFF);
    float* wcol = (float*)((char*)d_ws + WCOL_OFF);
    k_transW<<<dim3(1024), dim3(256), 0, stream>>>(W, Wt, wcol);
    k_convX<<<dim3(M_DIM), dim3(256), 0, stream>>>(X, wcol, b, Xb, adj);
    k_gemm8<<<dim3((M_DIM / 256) * (N_DIM / 256)), dim3(512), 0, stream>>>(
        Xb, Wt, b, adj, out);
  } else {
    k_gemm_f32<<<dim3((M_DIM / 16) * (N_DIM / 16)), dim3(256), 0, stream>>>(
        X, W, b, out);
    k_rowadj<<<dim3(M_DIM), dim3(256), 0, stream>>>(out);
  }
}

// Round 7
// 99.103 us; speedup vs baseline: 1.0381x; 1.0352x over previous
//
#include <hip/hip_runtime.h>
#include <hip/hip_bf16.h>
#include <stdint.h>

#define M_DIM 8192
#define N_DIM 2048
#define K_DIM 2048

typedef __attribute__((ext_vector_type(8))) short bf16x8;
typedef __attribute__((ext_vector_type(8))) short short8;
typedef __attribute__((ext_vector_type(4))) float f32x4;
typedef __attribute__((ext_vector_type(16))) float f32x16;

static __device__ __forceinline__ unsigned short f2bf(float f) {
  union { float f; unsigned u; } a; a.f = f;
  unsigned u = a.u;
  u += 0x7FFFu + ((u >> 16) & 1u);   // round-to-nearest-even
  return (unsigned short)(u >> 16);
}

static __device__ __forceinline__ void async16(void* lds, const void* g) {
  __builtin_amdgcn_global_load_lds(
      (const __attribute__((address_space(1))) unsigned int*)g,
      (__attribute__((address_space(3))) unsigned int*)lds, 16, 0, 0);
}

#define BAR()                                \
  do {                                       \
    asm volatile("" ::: "memory");           \
    __builtin_amdgcn_s_barrier();            \
    asm volatile("" ::: "memory");           \
  } while (0)
#define VMCNT(n) asm volatile("s_waitcnt vmcnt(" #n ")" ::: "memory")

// ---- kernel 1: convert + transpose W [K][N] -> Wt [N][K] bf16; fused
// W[:,0] extraction ----
__global__ __launch_bounds__(256) void k_transW(const float* __restrict__ W,
                                                unsigned short* __restrict__ Wt,
                                                float* __restrict__ wcol) {
  __shared__ float tile[64][65];
  const int bx = blockIdx.x & 31;
  const int by = blockIdx.x >> 5;
  const int n0 = bx * 64, k0 = by * 64;
  const int t = threadIdx.x;
  #pragma unroll
  for (int i = 0; i < 16; ++i) {
    int lin = i * 256 + t;
    int r = lin >> 6, c = lin & 63;
    float v = W[(size_t)(k0 + r) * N_DIM + n0 + c];
    tile[r][c] = v;
    if (bx == 0 && c == 0) wcol[k0 + r] = v;
  }
  __syncthreads();
  #pragma unroll
  for (int i = 0; i < 16; ++i) {
    int lin = i * 256 + t;
    int r = lin >> 6, c = lin & 63;
    Wt[(size_t)(n0 + r) * K_DIM + k0 + c] = f2bf(tile[c][r]);
  }
}

// ---- kernel 2: X fp32->bf16 + fused fp64 row-dot with W[:,0] -> adj ----
__global__ __launch_bounds__(256) void k_convX(const float* __restrict__ X,
    const float* __restrict__ wcol, const float* __restrict__ b,
    unsigned short* __restrict__ Xb, float* __restrict__ adj) {
  const int m = blockIdx.x;
  const int t = threadIdx.x;
  const float4* xr = (const float4*)(X + (size_t)m * K_DIM);
  const float4* wc = (const float4*)wcol;
  float4 x0 = xr[2 * t], x1 = xr[2 * t + 1];
  float4 w0 = wc[2 * t], w1 = wc[2 * t + 1];
  short8 o;
  o[0] = (short)f2bf(x0.x); o[1] = (short)f2bf(x0.y);
  o[2] = (short)f2bf(x0.z); o[3] = (short)f2bf(x0.w);
  o[4] = (short)f2bf(x1.x); o[5] = (short)f2bf(x1.y);
  o[6] = (short)f2bf(x1.z); o[7] = (short)f2bf(x1.w);
  *(short8*)(Xb + (size_t)m * K_DIM + t * 8) = o;
  double s = (double)x0.x * w0.x + (double)x0.y * w0.y +
             (double)x0.z * w0.z + (double)x0.w * w0.w +
             (double)x1.x * w1.x + (double)x1.y * w1.y +
             (double)x1.z * w1.z + (double)x1.w * w1.w;
  #pragma unroll
  for (int off = 32; off > 0; off >>= 1) s += __shfl_down(s, off, 64);
  __shared__ double red[4];
  if ((t & 63) == 0) red[t >> 6] = s;
  __syncthreads();
  if (t == 0) {
    double tot = red[0] + red[1] + red[2] + red[3] + (double)b[0];
    adj[m] = (tot > 0.5) ? 1.0f : -1.0f;
  }
}

// ---- kernel 3: 256x256 4-phase/K-tile MFMA GEMM, 32x32x16 shape ----
// Subtile (blk, ks) = 1024B holding A[blk*32..+32)[ks*16..+16) bf16.
// READ side uses the HW-verified-conflict-free round-3/4 mapping:
//   rdoff(l) = ((l&15)*64 + (l>>4)*16) ^ ((l&8)<<2)  (slot sigma(l))
// WRITE side compensates: gload_lds lane j writes slot j, so lane j's
// global source is chunk p = sigma^-1(j):
//   p = ((j>>2)&15) + 16*(j&1) + 32*(((j>>1)^(j>>5))&1)
//   (chunk p -> row p&31, khalf p>>5). Then slot sigma(l) holds lane l's
// fragment chunk (row=l&31, khalf=l>>5) for mfma_32x32x16.
// Sync skeleton (stage order A0,B0,B1,A1; vmcnt(4)@P2, vmcnt(2)@P4)
// byte-identical to rounds 3-6 (HW-validated race-free).
__device__ __forceinline__ void stage_unit(char* ldsc,
    const unsigned short* __restrict__ src, int row0, int kt,
    int isB, int sel, int wid, int l) {
  char* base = ldsc + (size_t)(kt & 1) * 65536 + (size_t)isB * 32768;
  const int p = ((l >> 2) & 15) + 16 * (l & 1) + 32 * (((l >> 1) ^ (l >> 5)) & 1);
  #pragma unroll
  for (int j = 0; j < 2; ++j) {
    int idx = wid * 2 + j;             // [0,16) subtile slots of this unit
    int q = idx >> 2, sc = idx & 3;
    int sr = isB ? (q * 2 + sel) : ((q & 1) + sel * 2 + (q >> 1) * 4);
    int grow = row0 + sr * 32 + (p & 31);
    int gcol = kt * 64 + sc * 16 + (p >> 5) * 8;
    async16(base + (size_t)(sr * 4 + sc) * 1024,
            src + (size_t)grow * K_DIM + gcol);
  }
}

__global__ __launch_bounds__(512, 1) void k_gemm8(
    const unsigned short* __restrict__ A,   // Xb [M][K] bf16
    const unsigned short* __restrict__ B,   // Wt [N][K] bf16
    const float* __restrict__ bias,
    const float* __restrict__ adj,
    float* __restrict__ out) {
  __shared__ unsigned short lds[2 * 2 * 256 * 64];   // 128 KB
  char* ldsc = (char*)lds;

  const int t = threadIdx.x;
  const int wid = t >> 6, l = t & 63;
  const int wm = wid >> 2, wn = wid & 3;

  // XCD-bijective swizzle (nwg = 256, 256 % 8 == 0)
  const int bid = blockIdx.x;
  const int swz = (bid & 7) * 32 + (bid >> 3);
  const int bm = swz >> 3, bn = swz & 7;
  const int m0 = bm * 256, n0 = bn * 256;

  // round-3/4 verified-conflict-free per-lane read offset (slot sigma(l)*16)
  const int rloc = l & 15, qloc = l >> 4;
  const int rdoff = (rloc * 64 + qloc * 16) ^ ((rloc & 8) << 2);

  f32x16 acc[4][2] = {};

#define STG(isB, sel, kt) \
  stage_unit(ldsc, (isB) ? B : A, (isB) ? n0 : m0, kt, isB, sel, wid, l)

#define RD_A(MH)                                                            \
  _Pragma("unroll") for (int mb2 = 0; mb2 < 2; ++mb2) {                     \
    const char* abase = ab +                                                \
        (size_t)((wm * 4 + (MH) * 2 + mb2) * 4) * 1024 + rdoff;             \
    _Pragma("unroll") for (int ks = 0; ks < 4; ++ks)                        \
      af[mb2][ks] = *(const bf16x8*)(abase + ks * 1024);                    \
  }

#define RD_B(DST, NH)                                                       \
  {                                                                         \
    const char* bbase = bb +                                                \
        (size_t)((wn * 2 + (NH)) * 4) * 1024 + rdoff;                       \
    _Pragma("unroll") for (int ks = 0; ks < 4; ++ks)                        \
      DST[ks] = *(const bf16x8*)(bbase + ks * 1024);                        \
  }

#define PHASE(BUF, MH, NH, READ_STMT, STAGE_STMT, WAIT_STMT)                \
  {                                                                         \
    const char* ab = ldsc + (size_t)(BUF) * 65536;                          \
    const char* bb = ab + 32768;                                            \
    (void)ab; (void)bb;                                                     \
    READ_STMT;                                                              \
    STAGE_STMT;                                                             \
    BAR();                                                                  \
    __builtin_amdgcn_s_setprio(1);                                          \
    _Pragma("unroll") for (int ks = 0; ks < 4; ++ks)                        \
      _Pragma("unroll") for (int mb2 = 0; mb2 < 2; ++mb2) {                 \
        acc[(MH) * 2 + mb2][NH] = __builtin_amdgcn_mfma_f32_32x32x16_bf16(  \
            af[mb2][ks], ((NH) ? bv1 : bv0)[ks], acc[(MH) * 2 + mb2][NH],   \
            0, 0, 0);                                                       \
      }                                                                     \
    __builtin_amdgcn_s_setprio(0);                                          \
    WAIT_STMT;                                                              \
    BAR();                                                                  \
  }

  // ---- prologue: stage tile 0 (A0,B0,B1,A1), retire all but A1(0) ----
  STG(0, 0, 0); STG(1, 0, 0); STG(1, 1, 0); STG(0, 1, 0);
  VMCNT(2);
  BAR();

  // ---- main loop: blocks j = 0..30, staging tile j+1 ----
  for (int j = 0; j < 31; ++j) {
    const int buf = j & 1;
    const int nt = j + 1;
    bf16x8 af[2][4], bv0[4], bv1[4];
    PHASE(buf, 0, 0, RD_A(0); RD_B(bv0, 0); RD_B(bv1, 1),
          STG(0, 0, nt), );                          // P1: stage A0(j+1)
    PHASE(buf, 0, 1, , STG(1, 0, nt), VMCNT(4));     // P2: B0(j+1); retire A1(j)
    PHASE(buf, 1, 0, RD_A(1), STG(1, 1, nt), );      // P3: stage B1(j+1)
    PHASE(buf, 1, 1, , STG(0, 1, nt), VMCNT(2));     // P4: A1(j+1); retire rest
  }
  // ---- peeled last block: tile 31 in buf1, drain ----
  {
    bf16x8 af[2][4], bv0[4], bv1[4];
    PHASE(1, 0, 0, RD_A(0); RD_B(bv0, 0); RD_B(bv1, 1), , );
    PHASE(1, 0, 1, , , VMCNT(0));                    // retire A1(31)
    PHASE(1, 1, 0, RD_A(1), , );
    PHASE(1, 1, 1, , , );
  }

#undef PHASE
#undef RD_A
#undef RD_B
#undef STG

  // ---- epilogue: bias + per-row +/-1 (32x32 C/D layout, validated) ----
  #pragma unroll
  for (int mb = 0; mb < 4; ++mb) {
    #pragma unroll
    for (int nb = 0; nb < 2; ++nb) {
      const int col = n0 + wn * 64 + nb * 32 + (l & 31);
      const float bvs = bias[col];
      #pragma unroll
      for (int rg = 0; rg < 4; ++rg) {
        const int rowb = m0 + wm * 128 + mb * 32 + rg * 8 + 4 * (l >> 5);
        const float4 adjv = *(const float4*)&adj[rowb];
        #pragma unroll
        for (int rr = 0; rr < 4; ++rr)
          out[(size_t)(rowb + rr) * N_DIM + col] =
              acc[mb][nb][rg * 4 + rr] + bvs + adjv[rr];
      }
    }
  }
}

// ---- fallback path (ws too small): fp32 LDS-tiled GEMM + row adjust ----
__global__ __launch_bounds__(256) void k_gemm_f32(const float* __restrict__ X,
    const float* __restrict__ W, const float* __restrict__ b,
    float* __restrict__ out) {
  __shared__ float As[16][16];
  __shared__ float Bs[16][17];
  const int bn = blockIdx.x & 127, bm = blockIdx.x >> 7;
  const int tx = threadIdx.x & 15, ty = threadIdx.x >> 4;
  const int row = bm * 16 + ty, col = bn * 16 + tx;
  float acc = 0.f;
  for (int k0 = 0; k0 < K_DIM; k0 += 16) {
    As[ty][tx] = X[(size_t)row * K_DIM + k0 + tx];
    Bs[ty][tx] = W[(size_t)(k0 + ty) * N_DIM + col];
    __syncthreads();
    #pragma unroll
    for (int kk = 0; kk < 16; ++kk) acc += As[ty][kk] * Bs[kk][tx];
    __syncthreads();
  }
  out[(size_t)row * N_DIM + col] = acc + b[col];
}

__global__ __launch_bounds__(256) void k_rowadj(float* __restrict__ out) {
  const int m = blockIdx.x;
  const float c0 = out[(size_t)m * N_DIM];
  __syncthreads();
  const float a = (c0 > 0.5f) ? 1.0f : -1.0f;
  for (int n = threadIdx.x; n < N_DIM; n += 256)
    out[(size_t)m * N_DIM + n] += a;
}

extern "C" void kernel_launch(void* const* d_in, const int* in_sizes, int n_in,
                              void* d_out, int out_size, void* d_ws, size_t ws_size,
                              hipStream_t stream) {
  const float* X = (const float*)d_in[0];
  const float* W = (const float*)d_in[1];
  const float* b = (const float*)d_in[2];
  float* out = (float*)d_out;

  const size_t XB_OFF   = 0;
  const size_t WT_OFF   = (size_t)M_DIM * K_DIM * 2;        // 32 MB
  const size_t ADJ_OFF  = WT_OFF + (size_t)N_DIM * K_DIM * 2;
  const size_t WCOL_OFF = ADJ_OFF + (size_t)M_DIM * 4;
  const size_t NEED     = WCOL_OFF + (size_t)K_DIM * 4;     // ~40 MB

  if (ws_size >= NEED) {
    unsigned short* Xb  = (unsigned short*)((char*)d_ws + XB_OFF);
    unsigned short* Wt  = (unsigned short*)((char*)d_ws + WT_OFF);
    float* adj  = (float*)((char*)d_ws + ADJ_OFF);
    float* wcol = (float*)((char*)d_ws + WCOL_OFF);
    k_transW<<<dim3(1024), dim3(256), 0, stream>>>(W, Wt, wcol);
    k_convX<<<dim3(M_DIM), dim3(256), 0, stream>>>(X, wcol, b, Xb, adj);
    k_gemm8<<<dim3((M_DIM / 256) * (N_DIM / 256)), dim3(512), 0, stream>>>(
        Xb, Wt, b, adj, out);
  } else {
    k_gemm_f32<<<dim3((M_DIM / 16) * (N_DIM / 16)), dim3(256), 0, stream>>>(
        X, W, b, out);
    k_rowadj<<<dim3(M_DIM), dim3(256), 0, stream>>>(out);
  }
}

// Round 8
// 98.681 us; speedup vs baseline: 1.0425x; 1.0043x over previous
//
#include <hip/hip_runtime.h>
#include <hip/hip_bf16.h>
#include <stdint.h>

#define M_DIM 8192
#define N_DIM 2048
#define K_DIM 2048

typedef __attribute__((ext_vector_type(8))) short bf16x8;
typedef __attribute__((ext_vector_type(8))) short short8;
typedef __attribute__((ext_vector_type(4))) float f32x4;
typedef __attribute__((ext_vector_type(16))) float f32x16;

static __device__ __forceinline__ unsigned short f2bf(float f) {
  union { float f; unsigned u; } a; a.f = f;
  unsigned u = a.u;
  u += 0x7FFFu + ((u >> 16) & 1u);   // round-to-nearest-even
  return (unsigned short)(u >> 16);
}

static __device__ __forceinline__ void async16(void* lds, const void* g) {
  __builtin_amdgcn_global_load_lds(
      (const __attribute__((address_space(1))) unsigned int*)g,
      (__attribute__((address_space(3))) unsigned int*)lds, 16, 0, 0);
}

#define BAR()                                \
  do {                                       \
    asm volatile("" ::: "memory");           \
    __builtin_amdgcn_s_barrier();            \
    asm volatile("" ::: "memory");           \
  } while (0)
#define VMCNT(n) asm volatile("s_waitcnt vmcnt(" #n ")" ::: "memory")

// ---- kernel 1: convert + transpose W [K][N] -> Wt [N][K] bf16; fused
// W[:,0] extraction ----
__global__ __launch_bounds__(256) void k_transW(const float* __restrict__ W,
                                                unsigned short* __restrict__ Wt,
                                                float* __restrict__ wcol) {
  __shared__ float tile[64][65];
  const int bx = blockIdx.x & 31;
  const int by = blockIdx.x >> 5;
  const int n0 = bx * 64, k0 = by * 64;
  const int t = threadIdx.x;
  #pragma unroll
  for (int i = 0; i < 16; ++i) {
    int lin = i * 256 + t;
    int r = lin >> 6, c = lin & 63;
    float v = W[(size_t)(k0 + r) * N_DIM + n0 + c];
    tile[r][c] = v;
    if (bx == 0 && c == 0) wcol[k0 + r] = v;
  }
  __syncthreads();
  #pragma unroll
  for (int i = 0; i < 16; ++i) {
    int lin = i * 256 + t;
    int r = lin >> 6, c = lin & 63;
    Wt[(size_t)(n0 + r) * K_DIM + k0 + c] = f2bf(tile[c][r]);
  }
}

// ---- kernel 2: X fp32->bf16 + fused fp64 row-dot with W[:,0] -> adj ----
__global__ __launch_bounds__(256) void k_convX(const float* __restrict__ X,
    const float* __restrict__ wcol, const float* __restrict__ b,
    unsigned short* __restrict__ Xb, float* __restrict__ adj) {
  const int m = blockIdx.x;
  const int t = threadIdx.x;
  const float4* xr = (const float4*)(X + (size_t)m * K_DIM);
  const float4* wc = (const float4*)wcol;
  float4 x0 = xr[2 * t], x1 = xr[2 * t + 1];
  float4 w0 = wc[2 * t], w1 = wc[2 * t + 1];
  short8 o;
  o[0] = (short)f2bf(x0.x); o[1] = (short)f2bf(x0.y);
  o[2] = (short)f2bf(x0.z); o[3] = (short)f2bf(x0.w);
  o[4] = (short)f2bf(x1.x); o[5] = (short)f2bf(x1.y);
  o[6] = (short)f2bf(x1.z); o[7] = (short)f2bf(x1.w);
  *(short8*)(Xb + (size_t)m * K_DIM + t * 8) = o;
  double s = (double)x0.x * w0.x + (double)x0.y * w0.y +
             (double)x0.z * w0.z + (double)x0.w * w0.w +
             (double)x1.x * w1.x + (double)x1.y * w1.y +
             (double)x1.z * w1.z + (double)x1.w * w1.w;
  #pragma unroll
  for (int off = 32; off > 0; off >>= 1) s += __shfl_down(s, off, 64);
  __shared__ double red[4];
  if ((t & 63) == 0) red[t >> 6] = s;
  __syncthreads();
  if (t == 0) {
    double tot = red[0] + red[1] + red[2] + red[3] + (double)b[0];
    adj[m] = (tot > 0.5) ? 1.0f : -1.0f;
  }
}

// ---- kernel 3: 256x256 4-phase/K-tile MFMA GEMM, 32x32x16 shape ----
// Data placement & sigma-mapping identical to round 7 (verified conflict-free,
// correct). NEW deep-pipelined stage schedule (latency-stall fix):
//   reads:  P1: A0+B0 (12 b128)  P2: B1 (4)  P3: A1 (8)  P4: none
//   stages: B0(j+1)@P1(j), B1(j+1)@P2(j), A1(j+1)@P3(j), A0(j+2)@P4(j)
//   waits:  vmcnt(6) at P1 (retires B1(j)), P2 (retires A1(j)),
//           P4 (retires A0(j+1), B0(j+1)); P3 none.
// Every unit's stage->retire distance >= 3 phases (~1800 cyc > ~900 HBM
// latency); 8-10 loads in flight, never drained to <4 in the main loop.
// Race-freedom: unit U(j+1) overwrites buffer slots of U(j-1), whose last
// LDS read is >= 4 barriers before the stage issue (A0/B0 read P1(j-1),
// B1 P2(j-1), A1 P3(j-1)).
__device__ __forceinline__ void stage_unit(char* ldsc,
    const unsigned short* __restrict__ src, int row0, int kt,
    int isB, int sel, int wid, int l) {
  char* base = ldsc + (size_t)(kt & 1) * 65536 + (size_t)isB * 32768;
  const int p = ((l >> 2) & 15) + 16 * (l & 1) + 32 * (((l >> 1) ^ (l >> 5)) & 1);
  #pragma unroll
  for (int j = 0; j < 2; ++j) {
    int idx = wid * 2 + j;             // [0,16) subtile slots of this unit
    int q = idx >> 2, sc = idx & 3;
    int sr = isB ? (q * 2 + sel) : ((q & 1) + sel * 2 + (q >> 1) * 4);
    int grow = row0 + sr * 32 + (p & 31);
    int gcol = kt * 64 + sc * 16 + (p >> 5) * 8;
    async16(base + (size_t)(sr * 4 + sc) * 1024,
            src + (size_t)grow * K_DIM + gcol);
  }
}

__global__ __launch_bounds__(512, 1) void k_gemm8(
    const unsigned short* __restrict__ A,   // Xb [M][K] bf16
    const unsigned short* __restrict__ B,   // Wt [N][K] bf16
    const float* __restrict__ bias,
    const float* __restrict__ adj,
    float* __restrict__ out) {
  __shared__ unsigned short lds[2 * 2 * 256 * 64];   // 128 KB
  char* ldsc = (char*)lds;

  const int t = threadIdx.x;
  const int wid = t >> 6, l = t & 63;
  const int wm = wid >> 2, wn = wid & 3;

  // XCD-bijective swizzle (nwg = 256, 256 % 8 == 0)
  const int bid = blockIdx.x;
  const int swz = (bid & 7) * 32 + (bid >> 3);
  const int bm = swz >> 3, bn = swz & 7;
  const int m0 = bm * 256, n0 = bn * 256;

  // verified-conflict-free per-lane read offset (slot sigma(l)*16)
  const int rloc = l & 15, qloc = l >> 4;
  const int rdoff = (rloc * 64 + qloc * 16) ^ ((rloc & 8) << 2);

  f32x16 acc[4][2] = {};

#define STG(isB, sel, kt) \
  stage_unit(ldsc, (isB) ? B : A, (isB) ? n0 : m0, kt, isB, sel, wid, l)

#define RD_A(MH)                                                            \
  _Pragma("unroll") for (int mb2 = 0; mb2 < 2; ++mb2) {                     \
    const char* abase = ab +                                                \
        (size_t)((wm * 4 + (MH) * 2 + mb2) * 4) * 1024 + rdoff;             \
    _Pragma("unroll") for (int ks = 0; ks < 4; ++ks)                        \
      af[mb2][ks] = *(const bf16x8*)(abase + ks * 1024);                    \
  }

#define RD_B(DST, NH)                                                       \
  {                                                                         \
    const char* bbase = bb +                                                \
        (size_t)((wn * 2 + (NH)) * 4) * 1024 + rdoff;                       \
    _Pragma("unroll") for (int ks = 0; ks < 4; ++ks)                        \
      DST[ks] = *(const bf16x8*)(bbase + ks * 1024);                        \
  }

#define PHASE(BUF, MH, NH, READ_STMT, STAGE_STMT, WAIT_STMT)                \
  {                                                                         \
    const char* ab = ldsc + (size_t)(BUF) * 65536;                          \
    const char* bb = ab + 32768;                                            \
    (void)ab; (void)bb;                                                     \
    READ_STMT;                                                              \
    STAGE_STMT;                                                             \
    BAR();                                                                  \
    __builtin_amdgcn_s_setprio(1);                                          \
    _Pragma("unroll") for (int ks = 0; ks < 4; ++ks)                        \
      _Pragma("unroll") for (int mb2 = 0; mb2 < 2; ++mb2) {                 \
        acc[(MH) * 2 + mb2][NH] = __builtin_amdgcn_mfma_f32_32x32x16_bf16(  \
            af[mb2][ks], ((NH) ? bv1 : bv0)[ks], acc[(MH) * 2 + mb2][NH],   \
            0, 0, 0);                                                       \
      }                                                                     \
    __builtin_amdgcn_s_setprio(0);                                          \
    WAIT_STMT;                                                              \
    BAR();                                                                  \
  }

  // ---- prologue: tile 0 fully + A0(1); retire A0(0),B0(0) only ----
  STG(0, 0, 0); STG(1, 0, 0); STG(1, 1, 0); STG(0, 1, 0);
  STG(0, 0, 1);
  VMCNT(6);
  BAR();

  // ---- main loop: j = 0..29 (tiles 0..29), deep-pipelined ----
  for (int j = 0; j < 30; ++j) {
    const int buf = j & 1;
    const int nt = j + 1;
    bf16x8 af[2][4], bv0[4], bv1[4];
    PHASE(buf, 0, 0, RD_A(0); RD_B(bv0, 0),
          STG(1, 0, nt), VMCNT(6));                // P1: stage B0(j+1); retire B1(j)
    PHASE(buf, 0, 1, RD_B(bv1, 1),
          STG(1, 1, nt), VMCNT(6));                // P2: stage B1(j+1); retire A1(j)
    PHASE(buf, 1, 0, RD_A(1),
          STG(0, 1, nt), );                        // P3: stage A1(j+1)
    PHASE(buf, 1, 1, ,
          STG(0, 0, nt + 1), VMCNT(6));            // P4: stage A0(j+2); retire A0/B0(j+1)
  }
  // ---- peeled j=30 (tile 30, buf0): no A0(32) to stage ----
  {
    bf16x8 af[2][4], bv0[4], bv1[4];
    PHASE(0, 0, 0, RD_A(0); RD_B(bv0, 0), STG(1, 0, 31), VMCNT(6));
    PHASE(0, 0, 1, RD_B(bv1, 1), STG(1, 1, 31), VMCNT(6));
    PHASE(0, 1, 0, RD_A(1), STG(0, 1, 31), );
    PHASE(0, 1, 1, , , VMCNT(4));                  // retire A0(31),B0(31)
  }
  // ---- peeled tile 31 (buf1): drain ----
  {
    bf16x8 af[2][4], bv0[4], bv1[4];
    PHASE(1, 0, 0, RD_A(0); RD_B(bv0, 0), , VMCNT(2));   // retire B1(31)
    PHASE(1, 0, 1, RD_B(bv1, 1), , VMCNT(0));            // retire A1(31)
    PHASE(1, 1, 0, RD_A(1), , );
    PHASE(1, 1, 1, , , );
  }

#undef PHASE
#undef RD_A
#undef RD_B
#undef STG

  // ---- epilogue: bias + per-row +/-1 (32x32 C/D layout, validated) ----
  #pragma unroll
  for (int mb = 0; mb < 4; ++mb) {
    #pragma unroll
    for (int nb = 0; nb < 2; ++nb) {
      const int col = n0 + wn * 64 + nb * 32 + (l & 31);
      const float bvs = bias[col];
      #pragma unroll
      for (int rg = 0; rg < 4; ++rg) {
        const int rowb = m0 + wm * 128 + mb * 32 + rg * 8 + 4 * (l >> 5);
        const float4 adjv = *(const float4*)&adj[rowb];
        #pragma unroll
        for (int rr = 0; rr < 4; ++rr)
          out[(size_t)(rowb + rr) * N_DIM + col] =
              acc[mb][nb][rg * 4 + rr] + bvs + adjv[rr];
      }
    }
  }
}

// ---- fallback path (ws too small): fp32 LDS-tiled GEMM + row adjust ----
__global__ __launch_bounds__(256) void k_gemm_f32(const float* __restrict__ X,
    const float* __restrict__ W, const float* __restrict__ b,
    float* __restrict__ out) {
  __shared__ float As[16][16];
  __shared__ float Bs[16][17];
  const int bn = blockIdx.x & 127, bm = blockIdx.x >> 7;
  const int tx = threadIdx.x & 15, ty = threadIdx.x >> 4;
  const int row = bm * 16 + ty, col = bn * 16 + tx;
  float acc = 0.f;
  for (int k0 = 0; k0 < K_DIM; k0 += 16) {
    As[ty][tx] = X[(size_t)row * K_DIM + k0 + tx];
    Bs[ty][tx] = W[(size_t)(k0 + ty) * N_DIM + col];
    __syncthreads();
    #pragma unroll
    for (int kk = 0; kk < 16; ++kk) acc += As[ty][kk] * Bs[kk][tx];
    __syncthreads();
  }
  out[(size_t)row * N_DIM + col] = acc + b[col];
}

__global__ __launch_bounds__(256) void k_rowadj(float* __restrict__ out) {
  const int m = blockIdx.x;
  const float c0 = out[(size_t)m * N_DIM];
  __syncthreads();
  const float a = (c0 > 0.5f) ? 1.0f : -1.0f;
  for (int n = threadIdx.x; n < N_DIM; n += 256)
    out[(size_t)m * N_DIM + n] += a;
}

extern "C" void kernel_launch(void* const* d_in, const int* in_sizes, int n_in,
                              void* d_out, int out_size, void* d_ws, size_t ws_size,
                              hipStream_t stream) {
  const float* X = (const float*)d_in[0];
  const float* W = (const float*)d_in[1];
  const float* b = (const float*)d_in[2];
  float* out = (float*)d_out;

  const size_t XB_OFF   = 0;
  const size_t WT_OFF   = (size_t)M_DIM * K_DIM * 2;        // 32 MB
  const size_t ADJ_OFF  = WT_OFF + (size_t)N_DIM * K_DIM * 2;
  const size_t WCOL_OFF = ADJ_OFF + (size_t)M_DIM * 4;
  const size_t NEED     = WCOL_OFF + (size_t)K_DIM * 4;     // ~40 MB

  if (ws_size >= NEED) {
    unsigned short* Xb  = (unsigned short*)((char*)d_ws + XB_OFF);
    unsigned short* Wt  = (unsigned short*)((char*)d_ws + WT_OFF);
    float* adj  = (float*)((char*)d_ws + ADJ_OFF);
    float* wcol = (float*)((char*)d_ws + WCOL_OFF);
    k_transW<<<dim3(1024), dim3(256), 0, stream>>>(W, Wt, wcol);
    k_convX<<<dim3(M_DIM), dim3(256), 0, stream>>>(X, wcol, b, Xb, adj);
    k_gemm8<<<dim3((M_DIM / 256) * (N_DIM / 256)), dim3(512), 0, stream>>>(
        Xb, Wt, b, adj, out);
  } else {
    k_gemm_f32<<<dim3((M_DIM / 16) * (N_DIM / 16)), dim3(256), 0, stream>>>(
        X, W, b, out);
    k_rowadj<<<dim3(M_DIM), dim3(256), 0, stream>>>(out);
  }
}